// Round 1
// baseline (1884.497 us; speedup 1.0000x reference)
//
#include <hip/hip_runtime.h>
#include <hip/hip_bf16.h>
#include <stdint.h>

#define NN 100000   // nodes
#define NE 800000   // edges
#define NG 4000     // graphs
// EMB=128, HID=256, FP=2048

__device__ __forceinline__ float b2f(unsigned short u) {
    return __uint_as_float(((unsigned int)u) << 16);
}
__device__ __forceinline__ unsigned short f2b(float f) {
    unsigned int x = __float_as_uint(f);
    x = x + 0x7FFFu + ((x >> 16) & 1u);   // RNE
    return (unsigned short)(x >> 16);
}

// ---------------- degree / CSR build ----------------
__global__ void k_count(const int* __restrict__ dst, int* __restrict__ cnt) {
    int e = blockIdx.x * 256 + threadIdx.x;
    if (e < NE) atomicAdd(&cnt[dst[e]], 1);
}

__global__ void k_dinv(const int* __restrict__ cnt, float* __restrict__ dinv) {
    int n = blockIdx.x * 256 + threadIdx.x;
    if (n < NN) dinv[n] = rsqrtf((float)(cnt[n] + 1));  // +1 self loop
}

__global__ __launch_bounds__(1024) void k_scan(const int* __restrict__ cnt,
                                               int* __restrict__ row_ptr,
                                               int* __restrict__ cursor) {
    __shared__ int s[1024];
    const int CH = (NN + 1023) / 1024;  // 98
    int tid = threadIdx.x;
    int lo = tid * CH, hi = min(lo + CH, NN);
    int sum = 0;
    for (int i = lo; i < hi; ++i) sum += cnt[i];
    s[tid] = sum;
    __syncthreads();
    for (int off = 1; off < 1024; off <<= 1) {
        int v = (tid >= off) ? s[tid - off] : 0;
        __syncthreads();
        s[tid] += v;
        __syncthreads();
    }
    int run = s[tid] - sum;  // exclusive prefix
    for (int i = lo; i < hi; ++i) {
        row_ptr[i] = run;
        cursor[i] = run;
        run += cnt[i];
    }
    if (tid == 1023) row_ptr[NN] = s[1023];
}

__global__ void k_fill(const int* __restrict__ src, const int* __restrict__ dst,
                       int* __restrict__ cursor, int* __restrict__ colA) {
    int e = blockIdx.x * 256 + threadIdx.x;
    if (e < NE) {
        int d = dst[e];
        int p = atomicAdd(&cursor[d], 1);
        colA[p] = src[e];
    }
}

// ---------------- GEMM: C[M,N] = op(A[M,K] @ B[K,N] (+bias) (relu)) ----------------
// GATHER: A is the concatenated embedding gather (K=384). ABF16: A is bf16. CBF16: C stored bf16.
template <bool GATHER, bool ABF16, bool BIAS, bool RELU, bool CBF16>
__global__ __launch_bounds__(256) void k_gemm(
    const void* __restrict__ Av, const float* __restrict__ B, void* __restrict__ Cv,
    const float* __restrict__ bias, int M, int N, int K,
    const int* __restrict__ ai, const int* __restrict__ di, const int* __restrict__ ci,
    const float* __restrict__ ea, const float* __restrict__ ed, const float* __restrict__ ec) {
    __shared__ float As[16][68];
    __shared__ float Bs[16][68];
    int tid = threadIdx.x;
    int row0 = blockIdx.x * 64, col0 = blockIdx.y * 64;
    int lr = tid >> 2, lk0 = (tid & 3) * 4;     // A-tile load coords
    int lkB = tid >> 4, ln0 = (tid & 15) * 4;   // B-tile load coords
    int arow = row0 + lr;
    int aoff = 0, doff = 0, coff = 0;
    if (GATHER) {
        int rr = (arow < M) ? arow : 0;
        aoff = ai[rr] * 128; doff = di[rr] * 128; coff = ci[rr] * 128;
    }
    const unsigned short* Ab = (const unsigned short*)Av;
    const float* Af = (const float*)Av;
    int ty = tid >> 4, tx = tid & 15;
    float acc[4][4] = {};

    for (int kb = 0; kb < K; kb += 16) {
        if (GATHER) {
#pragma unroll
            for (int i = 0; i < 4; ++i) {
                int k = kb + lk0 + i;
                float v = 0.f;
                if (arow < M)
                    v = (k < 128) ? ea[aoff + k] : (k < 256) ? ed[doff + k - 128] : ec[coff + k - 256];
                As[lk0 + i][lr] = v;
            }
        } else if (ABF16) {
            if (arow < M) {
                ushort4 u = *(const ushort4*)&Ab[(size_t)arow * K + kb + lk0];
                As[lk0 + 0][lr] = b2f(u.x); As[lk0 + 1][lr] = b2f(u.y);
                As[lk0 + 2][lr] = b2f(u.z); As[lk0 + 3][lr] = b2f(u.w);
            } else {
                As[lk0 + 0][lr] = 0.f; As[lk0 + 1][lr] = 0.f;
                As[lk0 + 2][lr] = 0.f; As[lk0 + 3][lr] = 0.f;
            }
        } else {
            if (arow < M) {
                float4 u = *(const float4*)&Af[(size_t)arow * K + kb + lk0];
                As[lk0 + 0][lr] = u.x; As[lk0 + 1][lr] = u.y;
                As[lk0 + 2][lr] = u.z; As[lk0 + 3][lr] = u.w;
            } else {
                As[lk0 + 0][lr] = 0.f; As[lk0 + 1][lr] = 0.f;
                As[lk0 + 2][lr] = 0.f; As[lk0 + 3][lr] = 0.f;
            }
        }
        {
            float4 u = *(const float4*)&B[(size_t)(kb + lkB) * N + col0 + ln0];
            Bs[lkB][ln0 + 0] = u.x; Bs[lkB][ln0 + 1] = u.y;
            Bs[lkB][ln0 + 2] = u.z; Bs[lkB][ln0 + 3] = u.w;
        }
        __syncthreads();
#pragma unroll
        for (int k = 0; k < 16; ++k) {
            float4 a = *(const float4*)&As[k][ty * 4];
            float4 b = *(const float4*)&Bs[k][tx * 4];
            acc[0][0] = fmaf(a.x, b.x, acc[0][0]); acc[0][1] = fmaf(a.x, b.y, acc[0][1]);
            acc[0][2] = fmaf(a.x, b.z, acc[0][2]); acc[0][3] = fmaf(a.x, b.w, acc[0][3]);
            acc[1][0] = fmaf(a.y, b.x, acc[1][0]); acc[1][1] = fmaf(a.y, b.y, acc[1][1]);
            acc[1][2] = fmaf(a.y, b.z, acc[1][2]); acc[1][3] = fmaf(a.y, b.w, acc[1][3]);
            acc[2][0] = fmaf(a.z, b.x, acc[2][0]); acc[2][1] = fmaf(a.z, b.y, acc[2][1]);
            acc[2][2] = fmaf(a.z, b.z, acc[2][2]); acc[2][3] = fmaf(a.z, b.w, acc[2][3]);
            acc[3][0] = fmaf(a.w, b.x, acc[3][0]); acc[3][1] = fmaf(a.w, b.y, acc[3][1]);
            acc[3][2] = fmaf(a.w, b.z, acc[3][2]); acc[3][3] = fmaf(a.w, b.w, acc[3][3]);
        }
        __syncthreads();
    }
#pragma unroll
    for (int i = 0; i < 4; ++i) {
        int r = row0 + ty * 4 + i;
        if (r < M) {
#pragma unroll
            for (int j = 0; j < 4; ++j) {
                int c = col0 + tx * 4 + j;
                float v = acc[i][j];
                if (BIAS) v += bias[c];
                if (RELU) v = fmaxf(v, 0.f);
                if (CBF16) ((unsigned short*)Cv)[(size_t)r * N + c] = f2b(v);
                else       ((float*)Cv)[(size_t)r * N + c] = v;
            }
        }
    }
}

// ---------------- GCN scatter (gather-at-dst form), h_out = relu(sum + b) ----------------
__global__ __launch_bounds__(256) void k_scatter(const unsigned short* __restrict__ xw,
                                                 unsigned short* __restrict__ hout,
                                                 const float* __restrict__ dinv,
                                                 const int* __restrict__ row_ptr,
                                                 const int* __restrict__ colA,
                                                 const float* __restrict__ bias) {
    int wid = threadIdx.x >> 6, lane = threadIdx.x & 63;
    int v = blockIdx.x * 4 + wid;
    if (v >= NN) return;
    float dv = dinv[v];
    int c0 = lane * 4;
    ushort4 sv = *(const ushort4*)&xw[(size_t)v * 256 + c0];
    float w0 = dv * dv;  // self-loop norm
    float a0 = b2f(sv.x) * w0, a1 = b2f(sv.y) * w0, a2 = b2f(sv.z) * w0, a3 = b2f(sv.w) * w0;
    int beg = row_ptr[v], end = row_ptr[v + 1];
    for (int p = beg; p < end; ++p) {
        int s = colA[p];
        float wn = dinv[s] * dv;
        ushort4 r = *(const ushort4*)&xw[(size_t)s * 256 + c0];
        a0 = fmaf(b2f(r.x), wn, a0);
        a1 = fmaf(b2f(r.y), wn, a1);
        a2 = fmaf(b2f(r.z), wn, a2);
        a3 = fmaf(b2f(r.w), wn, a3);
    }
    a0 = fmaxf(a0 + bias[c0 + 0], 0.f);
    a1 = fmaxf(a1 + bias[c0 + 1], 0.f);
    a2 = fmaxf(a2 + bias[c0 + 2], 0.f);
    a3 = fmaxf(a3 + bias[c0 + 3], 0.f);
    ushort4 o;
    o.x = f2b(a0); o.y = f2b(a1); o.z = f2b(a2); o.w = f2b(a3);
    *(ushort4*)&hout[(size_t)v * 256 + c0] = o;
}

// ---------------- graph boundaries from sorted batch ----------------
__global__ void k_bounds(const int* __restrict__ batch, int* __restrict__ gstart) {
    int n = blockIdx.x * 256 + threadIdx.x;
    if (n >= NN) return;
    int b = batch[n];
    if (n == 0) {
        for (int g = 0; g <= b; ++g) gstart[g] = 0;
    } else {
        int pb = batch[n - 1];
        if (pb != b)
            for (int g = pb + 1; g <= b; ++g) gstart[g] = n;
    }
    if (n == NN - 1) {
        for (int g = b + 1; g <= NG; ++g) gstart[g] = NN;
    }
}

// ---------------- pooling: pooled[g] = sum h[n] over nodes of g ----------------
__global__ __launch_bounds__(64) void k_pool(const unsigned short* __restrict__ h,
                                             const int* __restrict__ gstart,
                                             float* __restrict__ pooled) {
    int g = blockIdx.x;
    int lane = threadIdx.x;
    int c0 = lane * 4;
    int beg = gstart[g], end = gstart[g + 1];
    float a0 = 0.f, a1 = 0.f, a2 = 0.f, a3 = 0.f;
    for (int n = beg; n < end; ++n) {
        ushort4 r = *(const ushort4*)&h[(size_t)n * 256 + c0];
        a0 += b2f(r.x); a1 += b2f(r.y); a2 += b2f(r.z); a3 += b2f(r.w);
    }
    float4 o; o.x = a0; o.y = a1; o.z = a2; o.w = a3;
    *(float4*)&pooled[(size_t)g * 256 + c0] = o;
}

// ---------------- head: out[g] = relu([fp_emb, pooled] @ W1 + b1) @ W2 + b2 ----------------
__global__ __launch_bounds__(128) void k_head(const float* __restrict__ fp_emb,
                                              const float* __restrict__ pooled,
                                              const float* __restrict__ w1,
                                              const float* __restrict__ b1,
                                              const float* __restrict__ w2,
                                              const float* __restrict__ b2,
                                              float* __restrict__ out) {
    __shared__ float cat[512];
    __shared__ float red[128];
    int g = blockIdx.x, t = threadIdx.x;
    for (int i = t; i < 256; i += 128) cat[i] = fp_emb[(size_t)g * 256 + i];
    for (int i = t; i < 256; i += 128) cat[256 + i] = pooled[(size_t)g * 256 + i];
    __syncthreads();
    float s = b1[t];
    for (int i = 0; i < 512; ++i) s = fmaf(cat[i], w1[i * 128 + t], s);
    s = fmaxf(s, 0.f);
    red[t] = s * w2[t];
    __syncthreads();
    for (int off = 64; off > 0; off >>= 1) {
        if (t < off) red[t] += red[t + off];
        __syncthreads();
    }
    if (t == 0) out[g] = red[0] + b2[0];
}

// ---------------- launch ----------------
extern "C" void kernel_launch(void* const* d_in, const int* in_sizes, int n_in,
                              void* d_out, int out_size, void* d_ws, size_t ws_size,
                              hipStream_t stream) {
    const int* atom_idx   = (const int*)d_in[0];
    const int* degree_idx = (const int*)d_in[1];
    const int* charge_idx = (const int*)d_in[2];
    const int* edge_index = (const int*)d_in[3];
    const int* batch      = (const int*)d_in[4];
    const float* fingerprint = (const float*)d_in[5];
    const float* emb_atom   = (const float*)d_in[6];
    const float* emb_degree = (const float*)d_in[7];
    const float* emb_charge = (const float*)d_in[8];
    const float* proj_w1 = (const float*)d_in[9];
    const float* proj_b1 = (const float*)d_in[10];
    const float* proj_w2 = (const float*)d_in[11];
    const float* proj_b2 = (const float*)d_in[12];
    const float* fp_w = (const float*)d_in[13];
    const float* fp_b = (const float*)d_in[14];
    const float* conv_w[4] = {(const float*)d_in[15], (const float*)d_in[17],
                              (const float*)d_in[19], (const float*)d_in[21]};
    const float* conv_b[4] = {(const float*)d_in[16], (const float*)d_in[18],
                              (const float*)d_in[20], (const float*)d_in[22]};
    const float* lin1_w = (const float*)d_in[23];
    const float* lin1_b = (const float*)d_in[24];
    const float* lin2_w = (const float*)d_in[25];
    const float* lin2_b = (const float*)d_in[26];
    float* out = (float*)d_out;

    const int* src = edge_index;
    const int* dst = edge_index + NE;

    // workspace carve (256B aligned)
    char* p = (char*)d_ws;
    auto carve = [&](size_t bytes) { void* r = (void*)p; p += (bytes + 255) & ~(size_t)255; return r; };
    unsigned short* bufA = (unsigned short*)carve((size_t)NN * 256 * 2);  // h1 / xw
    unsigned short* bufB = (unsigned short*)carve((size_t)NN * 256 * 2);  // h0 / h
    int*   cnt     = (int*)carve((size_t)NN * 4);
    float* dinv    = (float*)carve((size_t)NN * 4);
    int*   row_ptr = (int*)carve((size_t)(NN + 1) * 4);
    int*   cursor  = (int*)carve((size_t)(NN + 1) * 4);
    int*   colA    = (int*)carve((size_t)NE * 4);
    int*   gstart  = (int*)carve((size_t)(NG + 1) * 4);
    float* pooled  = (float*)carve((size_t)NG * 256 * 4);
    float* fp_emb  = (float*)carve((size_t)NG * 256 * 4);

    // --- CSR build (layer-invariant) ---
    hipMemsetAsync(cnt, 0, (size_t)NN * 4, stream);
    k_count<<<(NE + 255) / 256, 256, 0, stream>>>(dst, cnt);
    k_dinv<<<(NN + 255) / 256, 256, 0, stream>>>(cnt, dinv);
    k_scan<<<1, 1024, 0, stream>>>(cnt, row_ptr, cursor);
    k_fill<<<(NE + 255) / 256, 256, 0, stream>>>(src, dst, cursor, colA);

    dim3 blk(256);
    int mg = (NN + 63) / 64;  // 1563

    // --- projector: h1 = relu(gather @ w1 + b1) -> bufA [NN,128] bf16 ---
    k_gemm<true, false, true, true, true><<<dim3(mg, 2), blk, 0, stream>>>(
        nullptr, proj_w1, bufA, proj_b1, NN, 128, 384,
        atom_idx, degree_idx, charge_idx, emb_atom, emb_degree, emb_charge);
    // --- h0 = h1 @ w2 + b2 -> bufB [NN,128] bf16 ---
    k_gemm<false, true, true, false, true><<<dim3(mg, 2), blk, 0, stream>>>(
        bufA, proj_w2, bufB, proj_b2, NN, 128, 128,
        nullptr, nullptr, nullptr, nullptr, nullptr, nullptr);

    // --- 4 GCN layers: xw = h @ w (bufB->bufA), scatter+bias+relu (bufA->bufB) ---
    int Kl = 128;
    for (int l = 0; l < 4; ++l) {
        k_gemm<false, true, false, false, true><<<dim3(mg, 4), blk, 0, stream>>>(
            bufB, conv_w[l], bufA, nullptr, NN, 256, Kl,
            nullptr, nullptr, nullptr, nullptr, nullptr, nullptr);
        k_scatter<<<NN / 4, 256, 0, stream>>>(bufA, bufB, dinv, row_ptr, colA, conv_b[l]);
        Kl = 256;
    }

    // --- pooling ---
    k_bounds<<<(NN + 255) / 256, 256, 0, stream>>>(batch, gstart);
    k_pool<<<NG, 64, 0, stream>>>(bufB, gstart, pooled);

    // --- fingerprint linear: fp_emb = fingerprint @ fp_w + fp_b (f32) ---
    k_gemm<false, false, true, false, false><<<dim3((NG + 63) / 64, 4), blk, 0, stream>>>(
        fingerprint, fp_w, fp_emb, fp_b, NG, 256, 2048,
        nullptr, nullptr, nullptr, nullptr, nullptr, nullptr);

    // --- head ---
    k_head<<<NG, 128, 0, stream>>>(fp_emb, pooled, lin1_w, lin1_b, lin2_w, lin2_b, out);
}

// Round 3
// 1071.113 us; speedup vs baseline: 1.7594x; 1.7594x over previous
//
#include <hip/hip_runtime.h>
#include <stdint.h>

#define NN 100000   // nodes
#define NE 800000   // edges
#define NG 4000     // graphs
#define NBLK ((NN + 255) / 256)   // 391 scan blocks

typedef __attribute__((ext_vector_type(8))) short s16x8;   // 8 bf16 (4 VGPRs)
typedef __attribute__((ext_vector_type(4))) float f32x4;

__device__ __forceinline__ float b2f(unsigned short u) {
    return __uint_as_float(((unsigned int)u) << 16);
}
__device__ __forceinline__ unsigned short f2b(float f) {
    unsigned int x = __float_as_uint(f);
    x = x + 0x7FFFu + ((x >> 16) & 1u);   // RNE
    return (unsigned short)(x >> 16);
}
__device__ __forceinline__ s16x8 cvt8(const float* __restrict__ p) {
    float4 a = *(const float4*)p;
    float4 b = *(const float4*)(p + 4);
    s16x8 r = {(short)f2b(a.x), (short)f2b(a.y), (short)f2b(a.z), (short)f2b(a.w),
               (short)f2b(b.x), (short)f2b(b.y), (short)f2b(b.z), (short)f2b(b.w)};
    return r;
}

// ---------------- degree / CSR build ----------------
__global__ void k_count(const int* __restrict__ dst, int* __restrict__ cnt) {
    int e = blockIdx.x * 256 + threadIdx.x;
    if (e < NE) atomicAdd(&cnt[dst[e]], 1);
}

__global__ void k_dinv(const int* __restrict__ cnt, float* __restrict__ dinv) {
    int n = blockIdx.x * 256 + threadIdx.x;
    if (n < NN) dinv[n] = rsqrtf((float)(cnt[n] + 1));  // +1 self loop
}

__global__ __launch_bounds__(256) void k_bsum(const int* __restrict__ cnt, int* __restrict__ bsum) {
    __shared__ int s[256];
    int i = blockIdx.x * 256 + threadIdx.x;
    s[threadIdx.x] = (i < NN) ? cnt[i] : 0;
    __syncthreads();
    for (int off = 128; off; off >>= 1) {
        if (threadIdx.x < off) s[threadIdx.x] += s[threadIdx.x + off];
        __syncthreads();
    }
    if (threadIdx.x == 0) bsum[blockIdx.x] = s[0];
}

__global__ __launch_bounds__(512) void k_bscan(const int* __restrict__ bsum, int* __restrict__ bpre) {
    __shared__ int s[512];
    int t = threadIdx.x;
    int v = (t < NBLK) ? bsum[t] : 0;
    s[t] = v;
    __syncthreads();
    for (int off = 1; off < 512; off <<= 1) {
        int u = (t >= off) ? s[t - off] : 0;
        __syncthreads();
        s[t] += u;
        __syncthreads();
    }
    if (t < NBLK) bpre[t] = s[t] - v;   // exclusive prefix of block sums
}

__global__ __launch_bounds__(256) void k_rowptr(const int* __restrict__ cnt, const int* __restrict__ bpre,
                                                int* __restrict__ row_ptr, int* __restrict__ cursor) {
    __shared__ int s[256];
    int t = threadIdx.x;
    int i = blockIdx.x * 256 + t;
    int v = (i < NN) ? cnt[i] : 0;
    s[t] = v;
    __syncthreads();
    for (int off = 1; off < 256; off <<= 1) {
        int u = (t >= off) ? s[t - off] : 0;
        __syncthreads();
        s[t] += u;
        __syncthreads();
    }
    if (i < NN) {
        int excl = bpre[blockIdx.x] + s[t] - v;
        row_ptr[i] = excl;
        cursor[i] = excl;
        if (i == NN - 1) row_ptr[NN] = NE;
    }
}

__global__ void k_fill(const int* __restrict__ src, const int* __restrict__ dst,
                       int* __restrict__ cursor, int* __restrict__ colA) {
    int e = blockIdx.x * 256 + threadIdx.x;
    if (e < NE) {
        int d = dst[e];
        int p = atomicAdd(&cursor[d], 1);
        colA[p] = src[e];
    }
}

// ---------------- weight transpose-convert: src f32 [K][N] -> dst bf16 [N][K] ----------------
__global__ void k_t(const float* __restrict__ src, unsigned short* __restrict__ dst, int KN, int ln) {
    int i = blockIdx.x * 256 + threadIdx.x;
    if (i < KN) {
        int k = i >> ln, n = i & ((1 << ln) - 1);
        dst[(size_t)n * (KN >> ln) + k] = f2b(src[i]);
    }
}

// fingerprint f32 -> bf16 (no transpose), 8 elems/thread
__global__ void k_cvt(const float* __restrict__ src, unsigned short* __restrict__ dst, int n8) {
    int i = blockIdx.x * 256 + threadIdx.x;
    if (i < n8) *(s16x8*)&dst[(size_t)i * 8] = cvt8(&src[(size_t)i * 8]);
}

// ---------------- MFMA GEMM: C[M,N] = op(A[M,K] @ B[K,N]) , Bt is bf16 [N][K] ----------------
// 256 thr = 4 waves (2x2), tile 128x128, per-wave 64x64, BK=32, 16x16x32 bf16 MFMA.
template <bool GATHER, bool BIAS, bool RELU, bool CBF16>
__global__ __launch_bounds__(256) void k_mm(
    const unsigned short* __restrict__ A, const unsigned short* __restrict__ Bt,
    void* __restrict__ Cv, const float* __restrict__ bias, int M, int N, int K,
    const int* __restrict__ ai, const int* __restrict__ di, const int* __restrict__ ci,
    const float* __restrict__ ea, const float* __restrict__ ed, const float* __restrict__ ec) {
    __shared__ unsigned short As[128 * 40];   // stride 40 shorts (80B): 2-way bank alias = free
    __shared__ unsigned short Bs[128 * 40];
    const int tid = threadIdx.x;
    const int row0 = blockIdx.x * 128, col0 = blockIdx.y * 128;
    const int lane = tid & 63, wid = tid >> 6;
    const int wrow = (wid >> 1) * 64, wcol = (wid & 1) * 64;
    const int lr = lane & 15, lk8 = (lane >> 4) * 8;

    const int sr = tid >> 1;          // staging row 0..127
    const int skc = (tid & 1) * 16;   // staging k offset {0,16}
    const int agrow = row0 + sr;
    const int bgrow = col0 + sr;      // Bt row (output col) — always < N (N % 128 == 0)
    int ia = 0, idg = 0, ic = 0;
    if (GATHER && agrow < M) { ia = ai[agrow] * 128; idg = di[agrow] * 128; ic = ci[agrow] * 128; }

    f32x4 acc[4][4] = {};

    for (int kb = 0; kb < K; kb += 32) {
        if (kb) __syncthreads();
#pragma unroll
        for (int c = 0; c < 2; ++c) {
            int kloc = skc + c * 8;
            s16x8 v = {};
            if (agrow < M) {
                if (GATHER) {
                    int kg = kb + kloc;
                    const float* p = (kg < 128) ? (ea + ia + kg)
                                   : (kg < 256) ? (ed + idg + kg - 128)
                                                : (ec + ic + kg - 256);
                    v = cvt8(p);
                } else {
                    v = *(const s16x8*)&A[(size_t)agrow * K + kb + kloc];
                }
            }
            *(s16x8*)&As[sr * 40 + kloc] = v;
            s16x8 w = *(const s16x8*)&Bt[(size_t)bgrow * K + kb + kloc];
            *(s16x8*)&Bs[sr * 40 + kloc] = w;
        }
        __syncthreads();
        s16x8 af[4], bfr[4];
#pragma unroll
        for (int f = 0; f < 4; ++f)
            af[f] = *(const s16x8*)&As[(wrow + f * 16 + lr) * 40 + lk8];
#pragma unroll
        for (int f = 0; f < 4; ++f)
            bfr[f] = *(const s16x8*)&Bs[(wcol + f * 16 + lr) * 40 + lk8];
#pragma unroll
        for (int fm = 0; fm < 4; ++fm)
#pragma unroll
            for (int fn = 0; fn < 4; ++fn)
                acc[fm][fn] = __builtin_amdgcn_mfma_f32_16x16x32_bf16(af[fm], bfr[fn], acc[fm][fn], 0, 0, 0);
    }
    // epilogue: D frag: col = lane&15, row = (lane>>4)*4 + r
#pragma unroll
    for (int fm = 0; fm < 4; ++fm) {
#pragma unroll
        for (int r = 0; r < 4; ++r) {
            int row = row0 + wrow + fm * 16 + (lane >> 4) * 4 + r;
            if (row < M) {
#pragma unroll
                for (int fn = 0; fn < 4; ++fn) {
                    int col = col0 + wcol + fn * 16 + lr;
                    float v = acc[fm][fn][r];
                    if (BIAS) v += bias[col];
                    if (RELU) v = fmaxf(v, 0.f);
                    if (CBF16) ((unsigned short*)Cv)[(size_t)row * N + col] = f2b(v);
                    else       ((float*)Cv)[(size_t)row * N + col] = v;
                }
            }
        }
    }
}

// ---------------- GCN scatter (gather-at-dst), h_out = relu(sum + b) ----------------
__global__ __launch_bounds__(256) void k_scatter(const unsigned short* __restrict__ xw,
                                                 unsigned short* __restrict__ hout,
                                                 const float* __restrict__ dinv,
                                                 const int* __restrict__ row_ptr,
                                                 const int* __restrict__ colA,
                                                 const float* __restrict__ bias) {
    int wid = threadIdx.x >> 6, lane = threadIdx.x & 63;
    int v = blockIdx.x * 4 + wid;
    if (v >= NN) return;
    float dv = dinv[v];
    int c0 = lane * 4;
    ushort4 sv = *(const ushort4*)&xw[(size_t)v * 256 + c0];
    float w0 = dv * dv;  // self-loop norm
    float a0 = b2f(sv.x) * w0, a1 = b2f(sv.y) * w0, a2 = b2f(sv.z) * w0, a3 = b2f(sv.w) * w0;
    int beg = row_ptr[v], end = row_ptr[v + 1];
    for (int p = beg; p < end; ++p) {
        int s = colA[p];
        float wn = dinv[s] * dv;
        ushort4 r = *(const ushort4*)&xw[(size_t)s * 256 + c0];
        a0 = fmaf(b2f(r.x), wn, a0);
        a1 = fmaf(b2f(r.y), wn, a1);
        a2 = fmaf(b2f(r.z), wn, a2);
        a3 = fmaf(b2f(r.w), wn, a3);
    }
    a0 = fmaxf(a0 + bias[c0 + 0], 0.f);
    a1 = fmaxf(a1 + bias[c0 + 1], 0.f);
    a2 = fmaxf(a2 + bias[c0 + 2], 0.f);
    a3 = fmaxf(a3 + bias[c0 + 3], 0.f);
    ushort4 o;
    o.x = f2b(a0); o.y = f2b(a1); o.z = f2b(a2); o.w = f2b(a3);
    *(ushort4*)&hout[(size_t)v * 256 + c0] = o;
}

// ---------------- graph boundaries from sorted batch ----------------
__global__ void k_bounds(const int* __restrict__ batch, int* __restrict__ gstart) {
    int n = blockIdx.x * 256 + threadIdx.x;
    if (n >= NN) return;
    int b = batch[n];
    if (n == 0) {
        for (int g = 0; g <= b; ++g) gstart[g] = 0;
    } else {
        int pb = batch[n - 1];
        if (pb != b)
            for (int g = pb + 1; g <= b; ++g) gstart[g] = n;
    }
    if (n == NN - 1) {
        for (int g = b + 1; g <= NG; ++g) gstart[g] = NN;
    }
}

// ---------------- pooling ----------------
__global__ __launch_bounds__(64) void k_pool(const unsigned short* __restrict__ h,
                                             const int* __restrict__ gstart,
                                             float* __restrict__ pooled) {
    int g = blockIdx.x;
    int lane = threadIdx.x;
    int c0 = lane * 4;
    int beg = gstart[g], end = gstart[g + 1];
    float a0 = 0.f, a1 = 0.f, a2 = 0.f, a3 = 0.f;
    for (int n = beg; n < end; ++n) {
        ushort4 r = *(const ushort4*)&h[(size_t)n * 256 + c0];
        a0 += b2f(r.x); a1 += b2f(r.y); a2 += b2f(r.z); a3 += b2f(r.w);
    }
    float4 o; o.x = a0; o.y = a1; o.z = a2; o.w = a3;
    *(float4*)&pooled[(size_t)g * 256 + c0] = o;
}

// ---------------- head ----------------
__global__ __launch_bounds__(128) void k_head(const float* __restrict__ fp_emb,
                                              const float* __restrict__ pooled,
                                              const float* __restrict__ w1,
                                              const float* __restrict__ b1,
                                              const float* __restrict__ w2,
                                              const float* __restrict__ b2,
                                              float* __restrict__ out) {
    __shared__ float cat[512];
    __shared__ float red[128];
    int g = blockIdx.x, t = threadIdx.x;
    for (int i = t; i < 256; i += 128) cat[i] = fp_emb[(size_t)g * 256 + i];
    for (int i = t; i < 256; i += 128) cat[256 + i] = pooled[(size_t)g * 256 + i];
    __syncthreads();
    float s = b1[t];
    for (int i = 0; i < 512; ++i) s = fmaf(cat[i], w1[i * 128 + t], s);
    s = fmaxf(s, 0.f);
    red[t] = s * w2[t];
    __syncthreads();
    for (int off = 64; off > 0; off >>= 1) {
        if (t < off) red[t] += red[t + off];
        __syncthreads();
    }
    if (t == 0) out[g] = red[0] + b2[0];
}

// ---------------- launch ----------------
extern "C" void kernel_launch(void* const* d_in, const int* in_sizes, int n_in,
                              void* d_out, int out_size, void* d_ws, size_t ws_size,
                              hipStream_t stream) {
    const int* atom_idx   = (const int*)d_in[0];
    const int* degree_idx = (const int*)d_in[1];
    const int* charge_idx = (const int*)d_in[2];
    const int* edge_index = (const int*)d_in[3];
    const int* batch      = (const int*)d_in[4];
    const float* fingerprint = (const float*)d_in[5];
    const float* emb_atom   = (const float*)d_in[6];
    const float* emb_degree = (const float*)d_in[7];
    const float* emb_charge = (const float*)d_in[8];
    const float* proj_w1 = (const float*)d_in[9];
    const float* proj_b1 = (const float*)d_in[10];
    const float* proj_w2 = (const float*)d_in[11];
    const float* proj_b2 = (const float*)d_in[12];
    const float* fp_w = (const float*)d_in[13];
    const float* fp_b = (const float*)d_in[14];
    const float* conv_w[4] = {(const float*)d_in[15], (const float*)d_in[17],
                              (const float*)d_in[19], (const float*)d_in[21]};
    const float* conv_b[4] = {(const float*)d_in[16], (const float*)d_in[18],
                              (const float*)d_in[20], (const float*)d_in[22]};
    const float* lin1_w = (const float*)d_in[23];
    const float* lin1_b = (const float*)d_in[24];
    const float* lin2_w = (const float*)d_in[25];
    const float* lin2_b = (const float*)d_in[26];
    float* out = (float*)d_out;

    const int* src = edge_index;
    const int* dst = edge_index + NE;

    // workspace carve (256B aligned)
    char* p = (char*)d_ws;
    auto carve = [&](size_t bytes) { void* r = (void*)p; p += (bytes + 255) & ~(size_t)255; return r; };
    unsigned short* bufA = (unsigned short*)carve((size_t)NN * 256 * 2);  // h1 / xw
    unsigned short* bufB = (unsigned short*)carve((size_t)NN * 256 * 2);  // h0 / h
    int*   cnt     = (int*)carve((size_t)NN * 4);
    float* dinv    = (float*)carve((size_t)NN * 4);
    int*   row_ptr = (int*)carve((size_t)(NN + 1) * 4);
    int*   cursor  = (int*)carve((size_t)(NN + 1) * 4);
    int*   colA    = (int*)carve((size_t)NE * 4);
    int*   gstart  = (int*)carve((size_t)(NG + 1) * 4);
    float* pooled  = (float*)carve((size_t)NG * 256 * 4);
    float* fp_emb  = (float*)carve((size_t)NG * 256 * 4);
    int*   bsum    = (int*)carve((size_t)NBLK * 4);
    int*   bpre    = (int*)carve((size_t)NBLK * 4);
    unsigned short* w1t  = (unsigned short*)carve((size_t)128 * 384 * 2);
    unsigned short* w2t  = (unsigned short*)carve((size_t)128 * 128 * 2);
    unsigned short* cwt[4];
    cwt[0] = (unsigned short*)carve((size_t)256 * 128 * 2);
    for (int l = 1; l < 4; ++l) cwt[l] = (unsigned short*)carve((size_t)256 * 256 * 2);
    unsigned short* fpwt = (unsigned short*)carve((size_t)256 * 2048 * 2);
    unsigned short* fpbf = (unsigned short*)carve((size_t)NG * 2048 * 2);

    // --- CSR build (parallel scan) ---
    hipMemsetAsync(cnt, 0, (size_t)NN * 4, stream);
    k_count<<<(NE + 255) / 256, 256, 0, stream>>>(dst, cnt);
    k_dinv<<<(NN + 255) / 256, 256, 0, stream>>>(cnt, dinv);
    k_bsum<<<NBLK, 256, 0, stream>>>(cnt, bsum);
    k_bscan<<<1, 512, 0, stream>>>(bsum, bpre);
    k_rowptr<<<NBLK, 256, 0, stream>>>(cnt, bpre, row_ptr, cursor);
    k_fill<<<(NE + 255) / 256, 256, 0, stream>>>(src, dst, cursor, colA);

    // --- weight transpose-converts (f32 [K][N] -> bf16 [N][K]) ---
    k_t<<<(49152 + 255) / 256, 256, 0, stream>>>(proj_w1, w1t, 49152, 7);
    k_t<<<(16384 + 255) / 256, 256, 0, stream>>>(proj_w2, w2t, 16384, 7);
    k_t<<<(32768 + 255) / 256, 256, 0, stream>>>(conv_w[0], cwt[0], 32768, 8);
    for (int l = 1; l < 4; ++l)
        k_t<<<(65536 + 255) / 256, 256, 0, stream>>>(conv_w[l], cwt[l], 65536, 8);
    k_t<<<(524288 + 255) / 256, 256, 0, stream>>>(fp_w, fpwt, 524288, 8);
    k_cvt<<<(NG * 2048 / 8 + 255) / 256, 256, 0, stream>>>(fingerprint, fpbf, NG * 2048 / 8);

    const int mg = (NN + 127) / 128;  // 782

    // --- projector: h1 = relu(gather @ w1 + b1) -> bufA [NN,128] bf16 ---
    k_mm<true, true, true, true><<<dim3(mg, 1), 256, 0, stream>>>(
        nullptr, w1t, bufA, proj_b1, NN, 128, 384,
        atom_idx, degree_idx, charge_idx, emb_atom, emb_degree, emb_charge);
    // --- h0 = h1 @ w2 + b2 -> bufB [NN,128] bf16 ---
    k_mm<false, true, false, true><<<dim3(mg, 1), 256, 0, stream>>>(
        bufA, w2t, bufB, proj_b2, NN, 128, 128,
        nullptr, nullptr, nullptr, nullptr, nullptr, nullptr);

    // --- 4 GCN layers ---
    int Kl = 128;
    for (int l = 0; l < 4; ++l) {
        k_mm<false, false, false, true><<<dim3(mg, 2), 256, 0, stream>>>(
            bufB, cwt[l], bufA, nullptr, NN, 256, Kl,
            nullptr, nullptr, nullptr, nullptr, nullptr, nullptr);
        k_scatter<<<NN / 4, 256, 0, stream>>>(bufA, bufB, dinv, row_ptr, colA, conv_b[l]);
        Kl = 256;
    }

    // --- pooling ---
    k_bounds<<<(NN + 255) / 256, 256, 0, stream>>>(batch, gstart);
    k_pool<<<NG, 64, 0, stream>>>(bufB, gstart, pooled);

    // --- fingerprint linear (MFMA): fp_emb = fp_bf16 @ fp_w + fp_b (f32 out) ---
    k_mm<false, true, false, false><<<dim3((NG + 127) / 128, 2), 256, 0, stream>>>(
        fpbf, fpwt, fp_emb, fp_b, NG, 256, 2048,
        nullptr, nullptr, nullptr, nullptr, nullptr, nullptr);

    // --- head ---
    k_head<<<NG, 128, 0, stream>>>(fp_emb, pooled, lin1_w, lin1_b, lin2_w, lin2_b, out);
}

// Round 4
// 740.972 us; speedup vs baseline: 2.5433x; 1.4456x over previous
//
#include <hip/hip_runtime.h>
#include <stdint.h>

#define NN 100000   // nodes
#define NE 800000   // edges
#define NG 4000     // graphs
#define NBLK ((NN + 255) / 256)   // 391 scan blocks

typedef __attribute__((ext_vector_type(8))) short s16x8;   // 8 bf16 (4 VGPRs)
typedef __attribute__((ext_vector_type(4))) float f32x4;

__device__ __forceinline__ float b2f(unsigned short u) {
    return __uint_as_float(((unsigned int)u) << 16);
}
__device__ __forceinline__ unsigned short f2b(float f) {
    unsigned int x = __float_as_uint(f);
    x = x + 0x7FFFu + ((x >> 16) & 1u);   // RNE
    return (unsigned short)(x >> 16);
}
__device__ __forceinline__ s16x8 cvt8(const float* __restrict__ p) {
    float4 a = *(const float4*)p;
    float4 b = *(const float4*)(p + 4);
    s16x8 r = {(short)f2b(a.x), (short)f2b(a.y), (short)f2b(a.z), (short)f2b(a.w),
               (short)f2b(b.x), (short)f2b(b.y), (short)f2b(b.z), (short)f2b(b.w)};
    return r;
}

// ---------------- degree / CSR build ----------------
__global__ void k_count(const int* __restrict__ dst, int* __restrict__ cnt) {
    int e = blockIdx.x * 256 + threadIdx.x;
    if (e < NE) atomicAdd(&cnt[dst[e]], 1);
}

__global__ void k_dinv(const int* __restrict__ cnt, float* __restrict__ dinv) {
    int n = blockIdx.x * 256 + threadIdx.x;
    if (n < NN) dinv[n] = rsqrtf((float)(cnt[n] + 1));  // +1 self loop
}

__global__ __launch_bounds__(256) void k_bsum(const int* __restrict__ cnt, int* __restrict__ bsum) {
    __shared__ int s[256];
    int i = blockIdx.x * 256 + threadIdx.x;
    s[threadIdx.x] = (i < NN) ? cnt[i] : 0;
    __syncthreads();
    for (int off = 128; off; off >>= 1) {
        if (threadIdx.x < off) s[threadIdx.x] += s[threadIdx.x + off];
        __syncthreads();
    }
    if (threadIdx.x == 0) bsum[blockIdx.x] = s[0];
}

__global__ __launch_bounds__(512) void k_bscan(const int* __restrict__ bsum, int* __restrict__ bpre) {
    __shared__ int s[512];
    int t = threadIdx.x;
    int v = (t < NBLK) ? bsum[t] : 0;
    s[t] = v;
    __syncthreads();
    for (int off = 1; off < 512; off <<= 1) {
        int u = (t >= off) ? s[t - off] : 0;
        __syncthreads();
        s[t] += u;
        __syncthreads();
    }
    if (t < NBLK) bpre[t] = s[t] - v;   // exclusive prefix of block sums
}

__global__ __launch_bounds__(256) void k_rowptr(const int* __restrict__ cnt, const int* __restrict__ bpre,
                                                int* __restrict__ row_ptr, int* __restrict__ cursor) {
    __shared__ int s[256];
    int t = threadIdx.x;
    int i = blockIdx.x * 256 + t;
    int v = (i < NN) ? cnt[i] : 0;
    s[t] = v;
    __syncthreads();
    for (int off = 1; off < 256; off <<= 1) {
        int u = (t >= off) ? s[t - off] : 0;
        __syncthreads();
        s[t] += u;
        __syncthreads();
    }
    if (i < NN) {
        int excl = bpre[blockIdx.x] + s[t] - v;
        row_ptr[i] = excl;
        cursor[i] = excl;
        if (i == NN - 1) row_ptr[NN] = NE;
    }
}

__global__ void k_fill(const int* __restrict__ src, const int* __restrict__ dst,
                       int* __restrict__ cursor, int* __restrict__ colA) {
    int e = blockIdx.x * 256 + threadIdx.x;
    if (e < NE) {
        int d = dst[e];
        int p = atomicAdd(&cursor[d], 1);
        colA[p] = src[e];
    }
}

// ---------------- weight transpose-convert: src f32 [K][N] -> dst bf16 [N][K] ----------------
__global__ void k_t(const float* __restrict__ src, unsigned short* __restrict__ dst, int KN, int ln) {
    int i = blockIdx.x * 256 + threadIdx.x;
    if (i < KN) {
        int k = i >> ln, n = i & ((1 << ln) - 1);
        dst[(size_t)n * (KN >> ln) + k] = f2b(src[i]);
    }
}

// fingerprint f32 -> bf16 (no transpose), 8 elems/thread
__global__ void k_cvt(const float* __restrict__ src, unsigned short* __restrict__ dst, int n8) {
    int i = blockIdx.x * 256 + threadIdx.x;
    if (i < n8) *(s16x8*)&dst[(size_t)i * 8] = cvt8(&src[(size_t)i * 8]);
}

// ---------------- MFMA GEMM: C[M,N] = op(A[M,K] @ B[K,N]) , Bt is bf16 [N][K] ----------------
// 256 thr = 4 waves (2x2), tile 128x128, per-wave 64x64, BK=32, 16x16x32 bf16 MFMA.
template <bool GATHER, bool BIAS, bool RELU, bool CBF16>
__global__ __launch_bounds__(256) void k_mm(
    const unsigned short* __restrict__ A, const unsigned short* __restrict__ Bt,
    void* __restrict__ Cv, const float* __restrict__ bias, int M, int N, int K,
    const int* __restrict__ ai, const int* __restrict__ di, const int* __restrict__ ci,
    const float* __restrict__ ea, const float* __restrict__ ed, const float* __restrict__ ec) {
    __shared__ unsigned short As[128 * 40];   // stride 40 shorts (80B): 2-way bank alias = free
    __shared__ unsigned short Bs[128 * 40];
    const int tid = threadIdx.x;
    const int row0 = blockIdx.x * 128, col0 = blockIdx.y * 128;
    const int lane = tid & 63, wid = tid >> 6;
    const int wrow = (wid >> 1) * 64, wcol = (wid & 1) * 64;
    const int lr = lane & 15, lk8 = (lane >> 4) * 8;

    const int sr = tid >> 1;          // staging row 0..127
    const int skc = (tid & 1) * 16;   // staging k offset {0,16}
    const int agrow = row0 + sr;
    const int bgrow = col0 + sr;      // Bt row (output col) — always < N (N % 128 == 0)
    int ia = 0, idg = 0, ic = 0;
    if (GATHER && agrow < M) { ia = ai[agrow] * 128; idg = di[agrow] * 128; ic = ci[agrow] * 128; }

    f32x4 acc[4][4] = {};

    for (int kb = 0; kb < K; kb += 32) {
        if (kb) __syncthreads();
#pragma unroll
        for (int c = 0; c < 2; ++c) {
            int kloc = skc + c * 8;
            s16x8 v = {};
            if (agrow < M) {
                if (GATHER) {
                    int kg = kb + kloc;
                    const float* p = (kg < 128) ? (ea + ia + kg)
                                   : (kg < 256) ? (ed + idg + kg - 128)
                                                : (ec + ic + kg - 256);
                    v = cvt8(p);
                } else {
                    v = *(const s16x8*)&A[(size_t)agrow * K + kb + kloc];
                }
            }
            *(s16x8*)&As[sr * 40 + kloc] = v;
            s16x8 w = *(const s16x8*)&Bt[(size_t)bgrow * K + kb + kloc];
            *(s16x8*)&Bs[sr * 40 + kloc] = w;
        }
        __syncthreads();
        s16x8 af[4], bfr[4];
#pragma unroll
        for (int f = 0; f < 4; ++f)
            af[f] = *(const s16x8*)&As[(wrow + f * 16 + lr) * 40 + lk8];
#pragma unroll
        for (int f = 0; f < 4; ++f)
            bfr[f] = *(const s16x8*)&Bs[(wcol + f * 16 + lr) * 40 + lk8];
#pragma unroll
        for (int fm = 0; fm < 4; ++fm)
#pragma unroll
            for (int fn = 0; fn < 4; ++fn)
                acc[fm][fn] = __builtin_amdgcn_mfma_f32_16x16x32_bf16(af[fm], bfr[fn], acc[fm][fn], 0, 0, 0);
    }
    // epilogue: D frag: col = lane&15, row = (lane>>4)*4 + r
#pragma unroll
    for (int fm = 0; fm < 4; ++fm) {
#pragma unroll
        for (int r = 0; r < 4; ++r) {
            int row = row0 + wrow + fm * 16 + (lane >> 4) * 4 + r;
            if (row < M) {
#pragma unroll
                for (int fn = 0; fn < 4; ++fn) {
                    int col = col0 + wcol + fn * 16 + lr;
                    float v = acc[fm][fn][r];
                    if (BIAS) v += bias[col];
                    if (RELU) v = fmaxf(v, 0.f);
                    if (CBF16) ((unsigned short*)Cv)[(size_t)row * N + col] = f2b(v);
                    else       ((float*)Cv)[(size_t)row * N + col] = v;
                }
            }
        }
    }
}

// ---------------- GCN aggregate (gather-at-dst), W = feature width ----------------
// One wave per dst node. 16B/lane -> RPW edges processed concurrently per wave
// (2 for W=256, 4 for W=128), 2-deep unroll => up to 4 row-gathers in flight/wave.
// FUSE: apply +bias, relu (for S*(h@W)+b path); else pure aggregation.
template <int W, bool FUSE>
__global__ __launch_bounds__(256) void k_scat(const unsigned short* __restrict__ xw,
                                              unsigned short* __restrict__ hout,
                                              const float* __restrict__ dinv,
                                              const int* __restrict__ row_ptr,
                                              const int* __restrict__ colA,
                                              const float* __restrict__ bias) {
    constexpr int RPW = 1024 / W;   // edges in flight per wave: 128->4, 256->2
    constexpr int G = 64 / RPW;     // lanes per edge-row: 128->16, 256->32
    const int wid = threadIdx.x >> 6, lane = threadIdx.x & 63;
    const int v = blockIdx.x * 4 + wid;          // NN % 4 == 0
    const int grp = lane / G, li = lane % G;
    const int c0 = li * 8;
    const float dv = dinv[v];
    float acc[8] = {};
    const int beg = row_ptr[v], end = row_ptr[v + 1];
    int p = beg + grp;
    for (; p + RPW < end; p += 2 * RPW) {        // 2 edges per group per iter
        int s0 = colA[p], s1 = colA[p + RPW];
        float w0 = dinv[s0] * dv, w1 = dinv[s1] * dv;
        s16x8 r0 = *(const s16x8*)&xw[(size_t)s0 * W + c0];
        s16x8 r1 = *(const s16x8*)&xw[(size_t)s1 * W + c0];
#pragma unroll
        for (int j = 0; j < 8; ++j) acc[j] = fmaf(b2f((unsigned short)r0[j]), w0, acc[j]);
#pragma unroll
        for (int j = 0; j < 8; ++j) acc[j] = fmaf(b2f((unsigned short)r1[j]), w1, acc[j]);
    }
    if (p < end) {
        int s0 = colA[p];
        float w0 = dinv[s0] * dv;
        s16x8 r0 = *(const s16x8*)&xw[(size_t)s0 * W + c0];
#pragma unroll
        for (int j = 0; j < 8; ++j) acc[j] = fmaf(b2f((unsigned short)r0[j]), w0, acc[j]);
    }
    // cross-group reduction (groups cover identical col slices)
#pragma unroll
    for (int j = 0; j < 8; ++j) {
        if (RPW == 4) acc[j] += __shfl_xor(acc[j], 16);
        acc[j] += __shfl_xor(acc[j], 32);
    }
    // self loop + epilogue
    s16x8 rs = *(const s16x8*)&xw[(size_t)v * W + c0];
    const float ws = dv * dv;
    unsigned short o[8];
#pragma unroll
    for (int j = 0; j < 8; ++j) {
        float x = fmaf(b2f((unsigned short)rs[j]), ws, acc[j]);
        if (FUSE) x = fmaxf(x + bias[c0 + j], 0.f);
        o[j] = f2b(x);
    }
    if (grp == 0) *(s16x8*)&hout[(size_t)v * W + c0] = *(const s16x8*)o;
}

// ---------------- graph boundaries from sorted batch ----------------
__global__ void k_bounds(const int* __restrict__ batch, int* __restrict__ gstart) {
    int n = blockIdx.x * 256 + threadIdx.x;
    if (n >= NN) return;
    int b = batch[n];
    if (n == 0) {
        for (int g = 0; g <= b; ++g) gstart[g] = 0;
    } else {
        int pb = batch[n - 1];
        if (pb != b)
            for (int g = pb + 1; g <= b; ++g) gstart[g] = n;
    }
    if (n == NN - 1) {
        for (int g = b + 1; g <= NG; ++g) gstart[g] = NN;
    }
}

// ---------------- pooling ----------------
__global__ __launch_bounds__(64) void k_pool(const unsigned short* __restrict__ h,
                                             const int* __restrict__ gstart,
                                             float* __restrict__ pooled) {
    int g = blockIdx.x;
    int lane = threadIdx.x;
    int c0 = lane * 4;
    int beg = gstart[g], end = gstart[g + 1];
    float a0 = 0.f, a1 = 0.f, a2 = 0.f, a3 = 0.f;
    for (int n = beg; n < end; ++n) {
        ushort4 r = *(const ushort4*)&h[(size_t)n * 256 + c0];
        a0 += b2f(r.x); a1 += b2f(r.y); a2 += b2f(r.z); a3 += b2f(r.w);
    }
    float4 o; o.x = a0; o.y = a1; o.z = a2; o.w = a3;
    *(float4*)&pooled[(size_t)g * 256 + c0] = o;
}

// ---------------- head ----------------
__global__ __launch_bounds__(128) void k_head(const float* __restrict__ fp_emb,
                                              const float* __restrict__ pooled,
                                              const float* __restrict__ w1,
                                              const float* __restrict__ b1,
                                              const float* __restrict__ w2,
                                              const float* __restrict__ b2,
                                              float* __restrict__ out) {
    __shared__ float cat[512];
    __shared__ float red[128];
    int g = blockIdx.x, t = threadIdx.x;
    for (int i = t; i < 256; i += 128) cat[i] = fp_emb[(size_t)g * 256 + i];
    for (int i = t; i < 256; i += 128) cat[256 + i] = pooled[(size_t)g * 256 + i];
    __syncthreads();
    float s = b1[t];
    for (int i = 0; i < 512; ++i) s = fmaf(cat[i], w1[i * 128 + t], s);
    s = fmaxf(s, 0.f);
    red[t] = s * w2[t];
    __syncthreads();
    for (int off = 64; off > 0; off >>= 1) {
        if (t < off) red[t] += red[t + off];
        __syncthreads();
    }
    if (t == 0) out[g] = red[0] + b2[0];
}

// ---------------- launch ----------------
extern "C" void kernel_launch(void* const* d_in, const int* in_sizes, int n_in,
                              void* d_out, int out_size, void* d_ws, size_t ws_size,
                              hipStream_t stream) {
    const int* atom_idx   = (const int*)d_in[0];
    const int* degree_idx = (const int*)d_in[1];
    const int* charge_idx = (const int*)d_in[2];
    const int* edge_index = (const int*)d_in[3];
    const int* batch      = (const int*)d_in[4];
    const float* fingerprint = (const float*)d_in[5];
    const float* emb_atom   = (const float*)d_in[6];
    const float* emb_degree = (const float*)d_in[7];
    const float* emb_charge = (const float*)d_in[8];
    const float* proj_w1 = (const float*)d_in[9];
    const float* proj_b1 = (const float*)d_in[10];
    const float* proj_w2 = (const float*)d_in[11];
    const float* proj_b2 = (const float*)d_in[12];
    const float* fp_w = (const float*)d_in[13];
    const float* fp_b = (const float*)d_in[14];
    const float* conv_w[4] = {(const float*)d_in[15], (const float*)d_in[17],
                              (const float*)d_in[19], (const float*)d_in[21]};
    const float* conv_b[4] = {(const float*)d_in[16], (const float*)d_in[18],
                              (const float*)d_in[20], (const float*)d_in[22]};
    const float* lin1_w = (const float*)d_in[23];
    const float* lin1_b = (const float*)d_in[24];
    const float* lin2_w = (const float*)d_in[25];
    const float* lin2_b = (const float*)d_in[26];
    float* out = (float*)d_out;

    const int* src = edge_index;
    const int* dst = edge_index + NE;

    // workspace carve (256B aligned)
    char* p = (char*)d_ws;
    auto carve = [&](size_t bytes) { void* r = (void*)p; p += (bytes + 255) & ~(size_t)255; return r; };
    unsigned short* bufA = (unsigned short*)carve((size_t)NN * 256 * 2);  // h1 / xw
    unsigned short* bufB = (unsigned short*)carve((size_t)NN * 256 * 2);  // h0 / h
    int*   cnt     = (int*)carve((size_t)NN * 4);
    float* dinv    = (float*)carve((size_t)NN * 4);
    int*   row_ptr = (int*)carve((size_t)(NN + 1) * 4);
    int*   cursor  = (int*)carve((size_t)(NN + 1) * 4);
    int*   colA    = (int*)carve((size_t)NE * 4);
    int*   gstart  = (int*)carve((size_t)(NG + 1) * 4);
    float* pooled  = (float*)carve((size_t)NG * 256 * 4);
    float* fp_emb  = (float*)carve((size_t)NG * 256 * 4);
    int*   bsum    = (int*)carve((size_t)NBLK * 4);
    int*   bpre    = (int*)carve((size_t)NBLK * 4);
    unsigned short* w1t  = (unsigned short*)carve((size_t)128 * 384 * 2);
    unsigned short* w2t  = (unsigned short*)carve((size_t)128 * 128 * 2);
    unsigned short* cwt[4];
    cwt[0] = (unsigned short*)carve((size_t)256 * 128 * 2);
    for (int l = 1; l < 4; ++l) cwt[l] = (unsigned short*)carve((size_t)256 * 256 * 2);
    unsigned short* fpwt = (unsigned short*)carve((size_t)256 * 2048 * 2);
    unsigned short* fpbf = (unsigned short*)carve((size_t)NG * 2048 * 2);

    // --- CSR build (parallel scan) ---
    hipMemsetAsync(cnt, 0, (size_t)NN * 4, stream);
    k_count<<<(NE + 255) / 256, 256, 0, stream>>>(dst, cnt);
    k_dinv<<<(NN + 255) / 256, 256, 0, stream>>>(cnt, dinv);
    k_bsum<<<NBLK, 256, 0, stream>>>(cnt, bsum);
    k_bscan<<<1, 512, 0, stream>>>(bsum, bpre);
    k_rowptr<<<NBLK, 256, 0, stream>>>(cnt, bpre, row_ptr, cursor);
    k_fill<<<(NE + 255) / 256, 256, 0, stream>>>(src, dst, cursor, colA);

    // --- weight transpose-converts (f32 [K][N] -> bf16 [N][K]) ---
    k_t<<<(49152 + 255) / 256, 256, 0, stream>>>(proj_w1, w1t, 49152, 7);
    k_t<<<(16384 + 255) / 256, 256, 0, stream>>>(proj_w2, w2t, 16384, 7);
    k_t<<<(32768 + 255) / 256, 256, 0, stream>>>(conv_w[0], cwt[0], 32768, 8);
    for (int l = 1; l < 4; ++l)
        k_t<<<(65536 + 255) / 256, 256, 0, stream>>>(conv_w[l], cwt[l], 65536, 8);
    k_t<<<(524288 + 255) / 256, 256, 0, stream>>>(fp_w, fpwt, 524288, 8);
    k_cvt<<<(NG * 2048 / 8 + 255) / 256, 256, 0, stream>>>(fingerprint, fpbf, NG * 2048 / 8);

    const int mg = (NN + 127) / 128;  // 782

    // --- projector: h1 = relu(gather @ w1 + b1) -> bufA [NN,128] bf16 ---
    k_mm<true, true, true, true><<<dim3(mg, 1), 256, 0, stream>>>(
        nullptr, w1t, bufA, proj_b1, NN, 128, 384,
        atom_idx, degree_idx, charge_idx, emb_atom, emb_degree, emb_charge);
    // --- h0 = h1 @ w2 + b2 -> bufB [NN,128] bf16 ---
    k_mm<false, true, false, true><<<dim3(mg, 1), 256, 0, stream>>>(
        bufA, w2t, bufB, proj_b2, NN, 128, 128,
        nullptr, nullptr, nullptr, nullptr, nullptr, nullptr);

    // --- layer 0 reordered: S*(h@W) = (S*h)@W — aggregate on 128-wide h0 first ---
    k_scat<128, false><<<NN / 4, 256, 0, stream>>>(bufB, bufA, dinv, row_ptr, colA, nullptr);
    k_mm<false, true, true, true><<<dim3(mg, 2), 256, 0, stream>>>(
        bufA, cwt[0], bufB, conv_b[0], NN, 256, 128,
        nullptr, nullptr, nullptr, nullptr, nullptr, nullptr);

    // --- layers 1-3: GEMM then aggregate (+bias+relu fused) ---
    for (int l = 1; l < 4; ++l) {
        k_mm<false, false, false, true><<<dim3(mg, 2), 256, 0, stream>>>(
            bufB, cwt[l], bufA, nullptr, NN, 256, 256,
            nullptr, nullptr, nullptr, nullptr, nullptr, nullptr);
        k_scat<256, true><<<NN / 4, 256, 0, stream>>>(bufA, bufB, dinv, row_ptr, colA, conv_b[l]);
    }

    // --- pooling ---
    k_bounds<<<(NN + 255) / 256, 256, 0, stream>>>(batch, gstart);
    k_pool<<<NG, 64, 0, stream>>>(bufB, gstart, pooled);

    // --- fingerprint linear (MFMA): fp_emb = fp_bf16 @ fp_w + fp_b (f32 out) ---
    k_mm<false, true, false, false><<<dim3((NG + 127) / 128, 2), 256, 0, stream>>>(
        fpbf, fpwt, fp_emb, fp_b, NG, 256, 2048,
        nullptr, nullptr, nullptr, nullptr, nullptr, nullptr);

    // --- head ---
    k_head<<<NG, 128, 0, stream>>>(fp_emb, pooled, lin1_w, lin1_b, lin2_w, lin2_b, out);
}